// Round 2
// baseline (457.753 us; speedup 1.0000x reference)
//
#include <hip/hip_runtime.h>

#define EMB 1024
#define HID 4096
#define NB 2
#define TT 4096
#define MROWS (NB*TT)   // 8192
#define N1 (2*HID)      // 8192
#define NCHUNK 16
#define CHUNK 256

typedef short short8 __attribute__((ext_vector_type(8)));
typedef float v4f   __attribute__((ext_vector_type(4)));

__device__ __forceinline__ unsigned short f2bf(float f) {
  unsigned int u = __float_as_uint(f);
  u += 0x7FFFu + ((u >> 16) & 1u);
  return (unsigned short)(u >> 16);
}
__device__ __forceinline__ float bf2f(unsigned short s) {
  return __uint_as_float(((unsigned int)s) << 16);
}
__device__ __forceinline__ void g2l16(const void* g, void* l) {
  __builtin_amdgcn_global_load_lds(
      (const __attribute__((address_space(1))) void*)g,
      (__attribute__((address_space(3))) void*)l, 16, 0, 0);
}

__device__ __forceinline__ float block_reduce_sum(float v, float* sbuf) {
  #pragma unroll
  for (int off = 32; off; off >>= 1) v += __shfl_down(v, off, 64);
  int lane = threadIdx.x & 63, w = threadIdx.x >> 6;
  if (lane == 0) sbuf[w] = v;
  __syncthreads();
  return sbuf[0] + sbuf[1] + sbuf[2] + sbuf[3];
}

// ---------- weight converts ----------
__global__ __launch_bounds__(256) void conv_w12(const float* __restrict__ W1,
                                                const float* __restrict__ W2,
                                                unsigned short* __restrict__ o) {
  size_t i = ((size_t)blockIdx.x*256 + threadIdx.x)*4;
  const float* s = (i < (size_t)HID*EMB) ? (W1 + i) : (W2 + (i - (size_t)HID*EMB));
  float4 v = *(const float4*)s;
  ushort4 u; u.x=f2bf(v.x); u.y=f2bf(v.y); u.z=f2bf(v.z); u.w=f2bf(v.w);
  *(ushort4*)(o + i) = u;
}
__global__ __launch_bounds__(256) void conv_w3(const float* __restrict__ W3,
                                               unsigned short* __restrict__ o) {
  size_t i = ((size_t)blockIdx.x*256 + threadIdx.x)*4;
  float4 v = *(const float4*)(W3 + i);
  ushort4 u; u.x=f2bf(v.x); u.y=f2bf(v.y); u.z=f2bf(v.z); u.w=f2bf(v.w);
  *(ushort4*)(o + i) = u;
}

// ---------- rmsnorm (fp32 in, bf16 out), row = EMB ----------
__global__ __launch_bounds__(256) void rmsnorm_x(const float* __restrict__ x,
                                                 unsigned short* __restrict__ r) {
  __shared__ float sbuf[4];
  int row = blockIdx.x;
  float4 v = *(const float4*)(x + (size_t)row*EMB + threadIdx.x*4);
  float ss = v.x*v.x + v.y*v.y + v.z*v.z + v.w*v.w;
  float tot = block_reduce_sum(ss, sbuf);
  float sc = rsqrtf(tot * (1.0f/EMB) + 1e-6f);
  ushort4 o; o.x=f2bf(v.x*sc); o.y=f2bf(v.y*sc); o.z=f2bf(v.z*sc); o.w=f2bf(v.w*sc);
  *(ushort4*)(r + (size_t)row*EMB + threadIdx.x*4) = o;
}

// ---------- rmsnorm (bf16 in/out, IN-PLACE safe), row = HID ----------
__global__ __launch_bounds__(256) void rmsnorm_y(const unsigned short* __restrict__ y,
                                                 unsigned short* __restrict__ yn) {
  __shared__ float sbuf[4];
  int row = blockIdx.x;
  const unsigned short* p = y + (size_t)row*HID + threadIdx.x*16;
  short8 v0 = *(const short8*)p;
  short8 v1 = *(const short8*)(p+8);
  float f[16]; float ss = 0.f;
  #pragma unroll
  for (int j=0;j<8;++j){ f[j]=bf2f((unsigned short)v0[j]); f[j+8]=bf2f((unsigned short)v1[j]); }
  #pragma unroll
  for (int j=0;j<16;++j) ss += f[j]*f[j];
  float tot = block_reduce_sum(ss, sbuf);
  float sc = rsqrtf(tot*(1.0f/HID) + 1e-6f);
  short8 o0, o1;
  #pragma unroll
  for (int j=0;j<8;++j){ o0[j]=(short)f2bf(f[j]*sc); o1[j]=(short)f2bf(f[j+8]*sc); }
  unsigned short* q = yn + (size_t)row*HID + threadIdx.x*16;
  *(short8*)q = o0; *(short8*)(q+8) = o1;
}

// ---------- bf16 MFMA GEMM, C = A(MxK) * Bt(NxK)^T ----------
// MODE 0: Ch = (fp16) exp(acc)   MODE 1: Cf = acc + X
// 128x128 tile, BK=64, 256 thr (4 waves, 2x2 of 64x64), XOR-swizzled LDS.
template<int MODE>
__global__ __launch_bounds__(256, 2)
void gemm_bt(const unsigned short* __restrict__ A,
             const unsigned short* __restrict__ Bt,
             unsigned short* __restrict__ Ch,
             float* __restrict__ Cf,
             const float* __restrict__ X,
             int K, int N) {
  __shared__ short lA[128*64];
  __shared__ short lB[128*64];
  const int tid  = threadIdx.x;
  const int lane = tid & 63;
  const int wm   = (tid >> 6) >> 1, wn = (tid >> 6) & 1;
  const int rowBase = blockIdx.y * 128;
  const int colBase = blockIdx.x * 128;

  v4f acc[4][4];
  #pragma unroll
  for (int i=0;i<4;++i)
    #pragma unroll
    for (int j=0;j<4;++j) acc[i][j] = (v4f){0.f,0.f,0.f,0.f};

  for (int k0 = 0; k0 < K; k0 += 64) {
    // stage A,B tiles: slot s holds (row m = s>>3, logical 16B-chunk c = (s&7)^(m&7))
    #pragma unroll
    for (int j = 0; j < 4; ++j) {
      int s = j*256 + tid;
      int m = s >> 3;
      int c = (s & 7) ^ (m & 7);
      g2l16(A + (size_t)(rowBase + m)*K + k0 + c*8, &lA[s*8]);
    }
    #pragma unroll
    for (int j = 0; j < 4; ++j) {
      int s = j*256 + tid;
      int m = s >> 3;
      int c = (s & 7) ^ (m & 7);
      g2l16(Bt + (size_t)(colBase + m)*K + k0 + c*8, &lB[s*8]);
    }
    __syncthreads();
    #pragma unroll
    for (int s2 = 0; s2 < 2; ++s2) {
      const int quad = lane >> 4;
      const int cc = s2*4 + quad;           // logical 16B chunk for k = s2*32 + quad*8
      short8 aF[4], bF[4];
      #pragma unroll
      for (int mt = 0; mt < 4; ++mt) {
        int ml = wm*64 + mt*16 + (lane & 15);
        aF[mt] = *(const short8*)&lA[(ml*8 + (cc ^ (ml & 7)))*8];
      }
      #pragma unroll
      for (int nt = 0; nt < 4; ++nt) {
        int nl = wn*64 + nt*16 + (lane & 15);
        bF[nt] = *(const short8*)&lB[(nl*8 + (cc ^ (nl & 7)))*8];
      }
      #pragma unroll
      for (int mt = 0; mt < 4; ++mt)
        #pragma unroll
        for (int nt = 0; nt < 4; ++nt)
          acc[mt][nt] = __builtin_amdgcn_mfma_f32_16x16x32_bf16(aF[mt], bF[nt], acc[mt][nt], 0, 0, 0);
    }
    __syncthreads();
  }

  const int quad = lane >> 4, c15 = lane & 15;
  #pragma unroll
  for (int mt = 0; mt < 4; ++mt) {
    #pragma unroll
    for (int nt = 0; nt < 4; ++nt) {
      int col = colBase + wn*64 + nt*16 + c15;
      #pragma unroll
      for (int r = 0; r < 4; ++r) {
        int row = rowBase + wm*64 + mt*16 + quad*4 + r;
        size_t idx = (size_t)row*N + col;
        float v = acc[mt][nt][r];
        if (MODE == 0) {
          _Float16 h = (_Float16)__expf(v);
          Ch[idx] = *(unsigned short*)&h;
        } else {
          Cf[idx] = v + X[idx];
        }
      }
    }
  }
}

// ---------- chunked scan over t: ab holds exp(a)|exp(b) as fp16 [MROWS][N1] ----------
__global__ __launch_bounds__(256) void scan_partial(const unsigned short* __restrict__ ab,
                                                    float* __restrict__ part) {
  int col = blockIdx.x*256 + threadIdx.x;   // 0..8191
  int cy = blockIdx.y, bb = blockIdx.z;
  const unsigned short* p = ab + ((size_t)(bb*TT + cy*CHUNK))*N1 + col;
  float s = 0.f;
  #pragma unroll 8
  for (int i = 0; i < CHUNK; ++i) {
    unsigned short u = p[(size_t)i*N1];
    s += (float)(*(const _Float16*)&u);
  }
  part[((size_t)(bb*N1 + col))*NCHUNK + cy] = s;
}

__global__ __launch_bounds__(256) void scan_prefix(float* __restrict__ part) {
  int ch = blockIdx.x*256 + threadIdx.x;    // 0..16383
  size_t base = (size_t)ch*NCHUNK;
  float run = 0.f;
  #pragma unroll
  for (int c = 0; c < NCHUNK; ++c) { float v = part[base+c]; part[base+c] = run; run += v; }
}

__global__ __launch_bounds__(256) void scan_emit(const unsigned short* __restrict__ ab,
                                                 const float* __restrict__ part,
                                                 unsigned short* __restrict__ y) {
  int h = blockIdx.x*256 + threadIdx.x;     // 0..4095
  int cy = blockIdx.y, bb = blockIdx.z;
  float sa = part[((size_t)(bb*N1 + h))*NCHUNK + cy];
  float sb = part[((size_t)(bb*N1 + HID + h))*NCHUNK + cy];
  const unsigned short* pa = ab + ((size_t)(bb*TT + cy*CHUNK))*N1 + h;
  const unsigned short* pb = pa + HID;
  unsigned short* py = y + ((size_t)(bb*TT + cy*CHUNK))*HID + h;
  int t0 = cy*CHUNK;
  #pragma unroll 4
  for (int i = 0; i < CHUNK; ++i) {
    unsigned short ua = pa[(size_t)i*N1];
    unsigned short ub = pb[(size_t)i*N1];
    sa += (float)(*(const _Float16*)&ua);
    sb += (float)(*(const _Float16*)&ub);
    float inv = 1.0f / (float)(t0 + i + 1);
    py[(size_t)i*HID] = f2bf(sa*sb*inv*inv);
  }
}

extern "C" void kernel_launch(void* const* d_in, const int* in_sizes, int n_in,
                              void* d_out, int out_size, void* d_ws, size_t ws_size,
                              hipStream_t stream) {
  const float* x  = (const float*)d_in[0];
  const float* W1 = (const float*)d_in[1];
  const float* W2 = (const float*)d_in[2];
  const float* W3 = (const float*)d_in[3];
  float* out = (float*)d_out;
  char* ws = (char*)d_ws;

  // layout (233 MB total)
  unsigned short* r_bf   = (unsigned short*)(ws);                 // 16 MB
  unsigned short* w12_bf = (unsigned short*)(ws + 16777216ull);   // 16 MB
  unsigned short* w3_bf  = (unsigned short*)(ws + 33554432ull);   // 8 MB
  unsigned short* ab_h   = (unsigned short*)(ws + 41943040ull);   // 128 MB fp16
  unsigned short* y_bf   = (unsigned short*)(ws + 176160768ull);  // 64 MB
  float*          part   = (float*)(ws + 243269632ull);           // 1 MB

  conv_w12<<<8192, 256, 0, stream>>>(W1, W2, w12_bf);
  conv_w3<<<4096, 256, 0, stream>>>(W3, w3_bf);
  rmsnorm_x<<<MROWS, 256, 0, stream>>>(x, r_bf);
  gemm_bt<0><<<dim3(64,64), 256, 0, stream>>>(r_bf, w12_bf, ab_h, nullptr, nullptr, EMB, N1);
  scan_partial<<<dim3(32,16,2), 256, 0, stream>>>(ab_h, part);
  scan_prefix<<<64, 256, 0, stream>>>(part);
  scan_emit<<<dim3(16,16,2), 256, 0, stream>>>(ab_h, part, y_bf);
  rmsnorm_y<<<MROWS, 256, 0, stream>>>(y_bf, y_bf);
  gemm_bt<1><<<dim3(8,64), 256, 0, stream>>>(y_bf, w3_bf, nullptr, out, x, HID, EMB);
}

// Round 3
// 411.045 us; speedup vs baseline: 1.1136x; 1.1136x over previous
//
#include <hip/hip_runtime.h>

#define EMB 1024
#define HID 4096
#define NB 2
#define TT 4096
#define MROWS (NB*TT)   // 8192
#define N1 (2*HID)      // 8192
#define CHUNK 128       // = GEMM1 row tile
#define NCH 32          // chunks per batch (TT/CHUNK)

typedef short short8 __attribute__((ext_vector_type(8)));
typedef float v4f   __attribute__((ext_vector_type(4)));

__device__ __forceinline__ unsigned short f2bf(float f) {
  unsigned int u = __float_as_uint(f);
  u += 0x7FFFu + ((u >> 16) & 1u);
  return (unsigned short)(u >> 16);
}
__device__ __forceinline__ float bf2f(unsigned short s) {
  return __uint_as_float(((unsigned int)s) << 16);
}
__device__ __forceinline__ void g2l16(const void* g, void* l) {
  __builtin_amdgcn_global_load_lds(
      (const __attribute__((address_space(1))) void*)g,
      (__attribute__((address_space(3))) void*)l, 16, 0, 0);
}

__device__ __forceinline__ float block_reduce_sum(float v, float* sbuf) {
  #pragma unroll
  for (int off = 32; off; off >>= 1) v += __shfl_down(v, off, 64);
  int lane = threadIdx.x & 63, w = threadIdx.x >> 6;
  if (lane == 0) sbuf[w] = v;
  __syncthreads();
  return sbuf[0] + sbuf[1] + sbuf[2] + sbuf[3];
}

// ---------- weight converts ----------
__global__ __launch_bounds__(256) void conv_w12(const float* __restrict__ W1,
                                                const float* __restrict__ W2,
                                                unsigned short* __restrict__ o) {
  size_t i = ((size_t)blockIdx.x*256 + threadIdx.x)*4;
  const float* s = (i < (size_t)HID*EMB) ? (W1 + i) : (W2 + (i - (size_t)HID*EMB));
  float4 v = *(const float4*)s;
  ushort4 u; u.x=f2bf(v.x); u.y=f2bf(v.y); u.z=f2bf(v.z); u.w=f2bf(v.w);
  *(ushort4*)(o + i) = u;
}
__global__ __launch_bounds__(256) void conv_w3(const float* __restrict__ W3,
                                               unsigned short* __restrict__ o) {
  size_t i = ((size_t)blockIdx.x*256 + threadIdx.x)*4;
  float4 v = *(const float4*)(W3 + i);
  ushort4 u; u.x=f2bf(v.x); u.y=f2bf(v.y); u.z=f2bf(v.z); u.w=f2bf(v.w);
  *(ushort4*)(o + i) = u;
}

// ---------- rmsnorm (fp32 in, bf16 out), row = EMB ----------
__global__ __launch_bounds__(256) void rmsnorm_x(const float* __restrict__ x,
                                                 unsigned short* __restrict__ r) {
  __shared__ float sbuf[4];
  int row = blockIdx.x;
  float4 v = *(const float4*)(x + (size_t)row*EMB + threadIdx.x*4);
  float ss = v.x*v.x + v.y*v.y + v.z*v.z + v.w*v.w;
  float tot = block_reduce_sum(ss, sbuf);
  float sc = rsqrtf(tot * (1.0f/EMB) + 1e-6f);
  ushort4 o; o.x=f2bf(v.x*sc); o.y=f2bf(v.y*sc); o.z=f2bf(v.z*sc); o.w=f2bf(v.w*sc);
  *(ushort4*)(r + (size_t)row*EMB + threadIdx.x*4) = o;
}

// ---------- row sum-of-squares -> rsqrt scale (bf16 in), row = HID ----------
__global__ __launch_bounds__(256) void rowssq(const unsigned short* __restrict__ y,
                                              float* __restrict__ sc) {
  __shared__ float sbuf[4];
  int row = blockIdx.x;
  const unsigned short* p = y + (size_t)row*HID + threadIdx.x*16;
  short8 v0 = *(const short8*)p;
  short8 v1 = *(const short8*)(p+8);
  float ss = 0.f;
  #pragma unroll
  for (int j=0;j<8;++j){ float a=bf2f((unsigned short)v0[j]), b=bf2f((unsigned short)v1[j]); ss += a*a + b*b; }
  float tot = block_reduce_sum(ss, sbuf);
  if (threadIdx.x == 0) sc[row] = rsqrtf(tot*(1.0f/HID) + 1e-6f);
}

// ---------- bf16 MFMA GEMM, C = A(MxK) * Bt(NxK)^T ----------
// MODE 0: Ch = (fp16) exp(acc); per-block column sums -> part[col*64 + blockIdx.y]
// MODE 1: Cf = Sc[row]*acc + X
// 128x128 tile, BK=64, 256 thr (4 waves, 2x2 of 64x64), XOR-swizzled LDS.
template<int MODE>
__global__ __launch_bounds__(256, 2)
void gemm_bt(const unsigned short* __restrict__ A,
             const unsigned short* __restrict__ Bt,
             unsigned short* __restrict__ Ch,
             float* __restrict__ Cf,
             const float* __restrict__ X,
             const float* __restrict__ Sc,
             float* __restrict__ part,
             int K, int N) {
  __shared__ short lA[128*64];
  __shared__ short lB[128*64];
  __shared__ float cs[2][128];
  const int tid  = threadIdx.x;
  const int lane = tid & 63;
  const int wm   = (tid >> 6) >> 1, wn = (tid >> 6) & 1;
  const int rowBase = blockIdx.y * 128;
  const int colBase = blockIdx.x * 128;

  v4f acc[4][4];
  #pragma unroll
  for (int i=0;i<4;++i)
    #pragma unroll
    for (int j=0;j<4;++j) acc[i][j] = (v4f){0.f,0.f,0.f,0.f};

  for (int k0 = 0; k0 < K; k0 += 64) {
    #pragma unroll
    for (int j = 0; j < 4; ++j) {
      int s = j*256 + tid;
      int m = s >> 3;
      int c = (s & 7) ^ (m & 7);
      g2l16(A + (size_t)(rowBase + m)*K + k0 + c*8, &lA[s*8]);
    }
    #pragma unroll
    for (int j = 0; j < 4; ++j) {
      int s = j*256 + tid;
      int m = s >> 3;
      int c = (s & 7) ^ (m & 7);
      g2l16(Bt + (size_t)(colBase + m)*K + k0 + c*8, &lB[s*8]);
    }
    __syncthreads();
    #pragma unroll
    for (int s2 = 0; s2 < 2; ++s2) {
      const int quad = lane >> 4;
      const int cc = s2*4 + quad;
      short8 aF[4], bF[4];
      #pragma unroll
      for (int mt = 0; mt < 4; ++mt) {
        int ml = wm*64 + mt*16 + (lane & 15);
        aF[mt] = *(const short8*)&lA[(ml*8 + (cc ^ (ml & 7)))*8];
      }
      #pragma unroll
      for (int nt = 0; nt < 4; ++nt) {
        int nl = wn*64 + nt*16 + (lane & 15);
        bF[nt] = *(const short8*)&lB[(nl*8 + (cc ^ (nl & 7)))*8];
      }
      #pragma unroll
      for (int mt = 0; mt < 4; ++mt)
        #pragma unroll
        for (int nt = 0; nt < 4; ++nt)
          acc[mt][nt] = __builtin_amdgcn_mfma_f32_16x16x32_bf16(aF[mt], bF[nt], acc[mt][nt], 0, 0, 0);
    }
    __syncthreads();
  }

  const int quad = lane >> 4, c15 = lane & 15;
  float csum[4] = {0.f, 0.f, 0.f, 0.f};
  #pragma unroll
  for (int mt = 0; mt < 4; ++mt) {
    #pragma unroll
    for (int nt = 0; nt < 4; ++nt) {
      int col = colBase + wn*64 + nt*16 + c15;
      #pragma unroll
      for (int r = 0; r < 4; ++r) {
        int row = rowBase + wm*64 + mt*16 + quad*4 + r;
        size_t idx = (size_t)row*N + col;
        float v = acc[mt][nt][r];
        if (MODE == 0) {
          float e = __expf(v);
          _Float16 h = (_Float16)e;
          Ch[idx] = *(unsigned short*)&h;
          csum[nt] += e;
        } else {
          Cf[idx] = Sc[row]*v + X[idx];
        }
      }
    }
  }
  if (MODE == 0) {
    // reduce over quad (rows within wave), then across wm via LDS
    #pragma unroll
    for (int nt = 0; nt < 4; ++nt) {
      float s = csum[nt];
      s += __shfl_xor(s, 16, 64);
      s += __shfl_xor(s, 32, 64);
      if (lane < 16) cs[wm][wn*64 + nt*16 + lane] = s;
    }
    __syncthreads();
    if (tid < 128)
      part[(size_t)(colBase + tid)*64 + blockIdx.y] = cs[0][tid] + cs[1][tid];
  }
}

// ---------- exclusive prefix over 32 chunks per (col, batch) ----------
__global__ __launch_bounds__(256) void scan_prefix(float* __restrict__ part) {
  int idx = blockIdx.x*256 + threadIdx.x;   // 0..16383
  int col = idx >> 1, bb = idx & 1;
  float* p = part + (size_t)col*64 + bb*NCH;
  float run = 0.f;
  #pragma unroll
  for (int c = 0; c < NCH; ++c) { float v = p[c]; p[c] = run; run += v; }
}

// ---------- emit y = Sa*Sb/t^2 (bf16), scanning fp16 exp values ----------
__global__ __launch_bounds__(256) void scan_emit(const unsigned short* __restrict__ ab,
                                                 const float* __restrict__ part,
                                                 unsigned short* __restrict__ y) {
  int h = blockIdx.x*256 + threadIdx.x;     // 0..4095
  int cy = blockIdx.y, bb = blockIdx.z;
  float sa = part[(size_t)h*64 + bb*NCH + cy];
  float sb = part[(size_t)(HID + h)*64 + bb*NCH + cy];
  const unsigned short* pa = ab + ((size_t)(bb*TT + cy*CHUNK))*N1 + h;
  const unsigned short* pb = pa + HID;
  unsigned short* py = y + ((size_t)(bb*TT + cy*CHUNK))*HID + h;
  int t0 = cy*CHUNK;
  #pragma unroll 4
  for (int i = 0; i < CHUNK; ++i) {
    unsigned short ua = pa[(size_t)i*N1];
    unsigned short ub = pb[(size_t)i*N1];
    sa += (float)(*(const _Float16*)&ua);
    sb += (float)(*(const _Float16*)&ub);
    float inv = 1.0f / (float)(t0 + i + 1);
    py[(size_t)i*HID] = f2bf(sa*sb*inv*inv);
  }
}

extern "C" void kernel_launch(void* const* d_in, const int* in_sizes, int n_in,
                              void* d_out, int out_size, void* d_ws, size_t ws_size,
                              hipStream_t stream) {
  const float* x  = (const float*)d_in[0];
  const float* W1 = (const float*)d_in[1];
  const float* W2 = (const float*)d_in[2];
  const float* W3 = (const float*)d_in[3];
  float* out = (float*)d_out;
  char* ws = (char*)d_ws;

  unsigned short* r_bf   = (unsigned short*)(ws);                 // 16 MB
  unsigned short* w12_bf = (unsigned short*)(ws + 16777216ull);   // 16 MB
  unsigned short* w3_bf  = (unsigned short*)(ws + 33554432ull);   // 8 MB
  unsigned short* ab_h   = (unsigned short*)(ws + 41943040ull);   // 128 MB fp16
  unsigned short* y_bf   = (unsigned short*)(ws + 176160768ull);  // 64 MB
  // sc overlaps the (dead-after-scan_emit) head of ab
  float*          sc     = (float*)(ws + 41943040ull);            // 32 KB
  // part lives in d_out (32 MB; GEMM2 overwrites all of it at the end)
  float*          part   = (float*)d_out;                         // 2 MB

  conv_w12<<<8192, 256, 0, stream>>>(W1, W2, w12_bf);
  conv_w3<<<4096, 256, 0, stream>>>(W3, w3_bf);
  rmsnorm_x<<<MROWS, 256, 0, stream>>>(x, r_bf);
  gemm_bt<0><<<dim3(64,64), 256, 0, stream>>>(r_bf, w12_bf, ab_h, nullptr, nullptr, nullptr, part, EMB, N1);
  scan_prefix<<<64, 256, 0, stream>>>(part);
  scan_emit<<<dim3(16,NCH,2), 256, 0, stream>>>(ab_h, part, y_bf);
  rowssq<<<MROWS, 256, 0, stream>>>(y_bf, sc);
  gemm_bt<1><<<dim3(8,64), 256, 0, stream>>>(y_bf, w3_bf, nullptr, out, x, sc, nullptr, HID, EMB);
}